// Round 1
// baseline (151.900 us; speedup 1.0000x reference)
//
#include <hip/hip_runtime.h>
#include <stdint.h>

#define BATCH 8
#define SEQ   2048
#define DIM   256          // D == DV == 256
#define KVB   32
#define NKV   (SEQ / KVB)  // 64 kv tiles
#define NWT   16           // 512/32 W tiles

typedef __attribute__((ext_vector_type(8))) short bf16x8;
typedef __attribute__((ext_vector_type(4))) float f32x4;
typedef __attribute__((ext_vector_type(4))) unsigned int u32x4;

// ---- workspace layout (all bf16 tile images, MFMA-ready) ----
#define KT_BYTES 16384      // K tile: [32 kv][256 d], XOR-swizzled (byte ^= (row&7)<<4)
#define VT_BYTES 20480      // V/W tile: transposed [256][40] (32 valid + 8 pad bf16 per row)
#define K_WS_BYTES ((size_t)BATCH * NKV * KT_BYTES)   // 8 MiB
#define V_WS_OFF   K_WS_BYTES
#define V_WS_BYTES ((size_t)BATCH * NKV * VT_BYTES)   // 10 MiB
#define W_WS_OFF   (V_WS_OFF + V_WS_BYTES)
#define W_WS_BYTES ((size_t)NWT * VT_BYTES)           // 320 KiB

__device__ __forceinline__ unsigned short f2bf(float x) {
    unsigned u = __float_as_uint(x);
    unsigned r = u + 0x7fffu + ((u >> 16) & 1u);     // RNE
    return (unsigned short)(r >> 16);
}
__device__ __forceinline__ unsigned pack2(float a, float b) {
    return (unsigned)f2bf(a) | ((unsigned)f2bf(b) << 16);
}

// K -> bf16 XOR-swizzled [32][256] tiles (linear image; swizzle baked so LDS copy is linear)
__global__ void prep_k(const float* __restrict__ K, uint8_t* __restrict__ ws) {
    const int bid = blockIdx.x;                        // b*NKV + t (K is contiguous in (b,kv,d))
    const float* src = K + (size_t)bid * KVB * DIM;
    uint8_t* dst = ws + (size_t)bid * KT_BYTES;
    const int tid = threadIdx.x;
    const int c4 = tid & 63, r0 = tid >> 6;
#pragma unroll
    for (int p = 0; p < 8; ++p) {
        int r = r0 + p * 4;
        const float4 v = *(const float4*)(src + r * DIM + c4 * 4);
        uint2 w = make_uint2(pack2(v.x, v.y), pack2(v.z, v.w));
        unsigned off = ((unsigned)(r * 512 + c4 * 8)) ^ ((unsigned)((r & 7) << 4));
        *(uint2*)(dst + off) = w;
    }
}

// V (and W) -> bf16 transposed padded tiles [256][40]: row = free dim, cols = 32 contraction elems
__global__ void prep_t(const float* __restrict__ V, const float* __restrict__ W,
                       uint8_t* __restrict__ ws) {
    const int bid = blockIdx.x;
    const float* src;
    uint8_t* dst;
    if (bid < BATCH * NKV) {
        src = V + (size_t)bid * KVB * DIM;
        dst = ws + V_WS_OFF + (size_t)bid * VT_BYTES;
    } else {
        int t = bid - BATCH * NKV;
        src = W + (size_t)t * KVB * DIM;
        dst = ws + W_WS_OFF + (size_t)t * VT_BYTES;
    }
    const int c = threadIdx.x;                         // free-dim column 0..255
    unsigned u[16];
#pragma unroll
    for (int j = 0; j < 16; ++j)
        u[j] = pack2(src[(size_t)(2 * j) * DIM + c], src[(size_t)(2 * j + 1) * DIM + c]);
    uint8_t* row = dst + c * 80;
#pragma unroll
    for (int i = 0; i < 4; ++i) {
        u32x4 w = {u[4 * i], u[4 * i + 1], u[4 * i + 2], u[4 * i + 3]};
        *(u32x4*)(row + i * 16) = w;
    }
}

// smem map (54272 B):
//   attention: vbuf [0,20480) | kbuf [20480,36864) | P 4x[16][40]bf16 [36864,41984)
//   epilogue:  Wtile [0,20480) | ctx-bf16 4x[16][264] [20480,54272)
#define SMEM_BYTES 54272

__launch_bounds__(256, 2)
__global__ void attn_main(const float* __restrict__ Q, const float* __restrict__ bias,
                          const uint8_t* __restrict__ ws, float* __restrict__ out) {
    __shared__ __align__(16) uint8_t smem[SMEM_BYTES];
    uint8_t* vbuf = smem;
    uint8_t* kbuf = smem + 20480;
    const int tid = threadIdx.x;
    const int wid = tid >> 6, lane = tid & 63, g = lane >> 4, nn = lane & 15;
    uint8_t* pbuf = smem + 36864 + wid * 1280;
    const int b = blockIdx.x & 7, qt = blockIdx.x >> 3;   // batch -> XCD affinity
    const int q0 = qt * 64 + wid * 16;

    // Q fragments (A-layout: row = lane&15, k = t*32 + (lane>>4)*8 + j)
    bf16x8 qf[8];
    {
        const float* qrow = Q + ((size_t)b * SEQ + q0 + nn) * DIM + g * 8;
#pragma unroll
        for (int t = 0; t < 8; ++t) {
            float4 a = *(const float4*)(qrow + t * 32);
            float4 c = *(const float4*)(qrow + t * 32 + 4);
            union { bf16x8 v; unsigned u[4]; } tmp;
            tmp.u[0] = pack2(a.x, a.y); tmp.u[1] = pack2(a.z, a.w);
            tmp.u[2] = pack2(c.x, c.y); tmp.u[3] = pack2(c.z, c.w);
            qf[t] = tmp.v;
        }
    }

    f32x4 ctx[16];
#pragma unroll
    for (int d = 0; d < 16; ++d) ctx[d] = (f32x4){0.f, 0.f, 0.f, 0.f};
    float m[4] = {-1e30f, -1e30f, -1e30f, -1e30f};
    float l[4] = {0.f, 0.f, 0.f, 0.f};
    const float c1 = 0.0625f * 1.44269504088896f;   // scale * log2(e)

    const uint8_t* kws = ws + (size_t)b * NKV * KT_BYTES;
    const uint8_t* vws = ws + V_WS_OFF + (size_t)b * NKV * VT_BYTES;

    u32x4 kst[4], vst[5];
#pragma unroll
    for (int i = 0; i < 4; ++i) kst[i] = *(const u32x4*)(kws + tid * 16 + i * 4096);
#pragma unroll
    for (int i = 0; i < 5; ++i) vst[i] = *(const u32x4*)(vws + tid * 16 + i * 4096);

    for (int t = 0; t < NKV; ++t) {
        // commit staged regs to LDS (linear copy; swizzle baked into ws image)
#pragma unroll
        for (int i = 0; i < 4; ++i) *(u32x4*)(kbuf + tid * 16 + i * 4096) = kst[i];
#pragma unroll
        for (int i = 0; i < 5; ++i) *(u32x4*)(vbuf + tid * 16 + i * 4096) = vst[i];
        __syncthreads();
        if (t + 1 < NKV) {                       // issue next tile early; latency hides under MFMA
            const uint8_t* kn = kws + (size_t)(t + 1) * KT_BYTES;
            const uint8_t* vn = vws + (size_t)(t + 1) * VT_BYTES;
#pragma unroll
            for (int i = 0; i < 4; ++i) kst[i] = *(const u32x4*)(kn + tid * 16 + i * 4096);
#pragma unroll
            for (int i = 0; i < 5; ++i) vst[i] = *(const u32x4*)(vn + tid * 16 + i * 4096);
        }
        // ---- S = Q K^T (two 16x16 kv tiles) ----
        f32x4 s[2];
#pragma unroll
        for (int t2 = 0; t2 < 2; ++t2) {
            f32x4 acc = (f32x4){0.f, 0.f, 0.f, 0.f};
            int krow = t2 * 16 + nn;
            const uint8_t* kb = kbuf + krow * 512;
            unsigned sw = (unsigned)((krow & 7) << 4);
#pragma unroll
            for (int kk = 0; kk < 8; ++kk) {
                bf16x8 bf = *(const bf16x8*)(kb + (((unsigned)(kk * 64 + g * 16)) ^ sw));
                acc = __builtin_amdgcn_mfma_f32_16x16x32_bf16(qf[kk], bf, acc, 0, 0, 0);
            }
            s[t2] = acc;
        }
        // ---- online softmax (rows live on 16-lane groups; 4 rows/lane in reg dim) ----
        float sc[4];
#pragma unroll
        for (int r = 0; r < 4; ++r) {
            float v = fmaxf(s[0][r], s[1][r]);
            v = fmaxf(v, __shfl_xor(v, 1));
            v = fmaxf(v, __shfl_xor(v, 2));
            v = fmaxf(v, __shfl_xor(v, 4));
            v = fmaxf(v, __shfl_xor(v, 8));
            float mn = fmaxf(m[r], v);
            sc[r] = exp2f((m[r] - mn) * c1);
            m[r] = mn;
        }
#pragma unroll
        for (int r = 0; r < 4; ++r) {
            float p0 = exp2f((s[0][r] - m[r]) * c1);
            float p1 = exp2f((s[1][r] - m[r]) * c1);
            float rs = p0 + p1;
            rs += __shfl_xor(rs, 1);
            rs += __shfl_xor(rs, 2);
            rs += __shfl_xor(rs, 4);
            rs += __shfl_xor(rs, 8);
            l[r] = l[r] * sc[r] + rs;
            *(unsigned short*)(pbuf + (g * 4 + r) * 80 + nn * 2)      = f2bf(p0);
            *(unsigned short*)(pbuf + (g * 4 + r) * 80 + 32 + nn * 2) = f2bf(p1);
        }
#pragma unroll
        for (int d = 0; d < 16; ++d) {
#pragma unroll
            for (int r = 0; r < 4; ++r) ctx[d][r] *= sc[r];
        }
        // ---- ctx += P V (P via per-wave LDS transpose; wave-internal, no barrier) ----
        bf16x8 pa = *(const bf16x8*)(pbuf + nn * 80 + g * 16);
#pragma unroll
        for (int d = 0; d < 16; ++d) {
            bf16x8 vf = *(const bf16x8*)(vbuf + (size_t)(d * 16 + nn) * 80 + g * 16);
            ctx[d] = __builtin_amdgcn_mfma_f32_16x16x32_bf16(pa, vf, ctx[d], 0, 0, 0);
        }
        __syncthreads();
    }

    // ---- epilogue: out = [ctx, Q] @ W + b (fused; ctx never hits HBM) ----
    uint8_t* cb = smem + 20480 + wid * 8448;     // per-wave [16][264] bf16, stride 528 B
    float il[4];
#pragma unroll
    for (int r = 0; r < 4; ++r) il[r] = 1.0f / l[r];
#pragma unroll
    for (int d = 0; d < 16; ++d) {
#pragma unroll
        for (int r = 0; r < 4; ++r)
            *(unsigned short*)(cb + (g * 4 + r) * 528 + (d * 16 + nn) * 2) = f2bf(ctx[d][r] * il[r]);
    }
#pragma unroll
    for (int d = 0; d < 16; ++d) ctx[d] = (f32x4){0.f, 0.f, 0.f, 0.f};

    const uint8_t* wws = ws + W_WS_OFF;
#pragma unroll
    for (int i = 0; i < 5; ++i) vst[i] = *(const u32x4*)(wws + tid * 16 + i * 4096);

    for (int wt = 0; wt < NWT; ++wt) {
#pragma unroll
        for (int i = 0; i < 5; ++i) *(u32x4*)(vbuf + tid * 16 + i * 4096) = vst[i];
        __syncthreads();
        if (wt + 1 < NWT) {
            const uint8_t* wn = wws + (size_t)(wt + 1) * VT_BYTES;
#pragma unroll
            for (int i = 0; i < 5; ++i) vst[i] = *(const u32x4*)(wn + tid * 16 + i * 4096);
        }
        bf16x8 af;
        if (wt < 8) af = *(const bf16x8*)(cb + nn * 528 + wt * 64 + g * 16);  // context half
        else        af = qf[wt - 8];                                          // query half
#pragma unroll
        for (int d = 0; d < 16; ++d) {
            bf16x8 wf = *(const bf16x8*)(vbuf + (size_t)(d * 16 + nn) * 80 + g * 16);
            ctx[d] = __builtin_amdgcn_mfma_f32_16x16x32_bf16(af, wf, ctx[d], 0, 0, 0);
        }
        __syncthreads();
    }

    float* orow = out + ((size_t)b * SEQ + q0) * DIM;
#pragma unroll
    for (int d = 0; d < 16; ++d) {
        float bv = bias[d * 16 + nn];
#pragma unroll
        for (int r = 0; r < 4; ++r)
            orow[(size_t)(g * 4 + r) * DIM + d * 16 + nn] = ctx[d][r] + bv;
    }
}

extern "C" void kernel_launch(void* const* d_in, const int* in_sizes, int n_in,
                              void* d_out, int out_size, void* d_ws, size_t ws_size,
                              hipStream_t stream) {
    const float* Q    = (const float*)d_in[0];
    const float* K    = (const float*)d_in[1];
    const float* V    = (const float*)d_in[2];
    const float* W    = (const float*)d_in[3];
    const float* bias = (const float*)d_in[4];
    float* out = (float*)d_out;
    uint8_t* ws = (uint8_t*)d_ws;
    prep_k<<<BATCH * NKV, 256, 0, stream>>>(K, ws);
    prep_t<<<BATCH * NKV + NWT, 256, 0, stream>>>(V, W, ws);
    attn_main<<<256, 256, 0, stream>>>(Q, bias, ws, out);
}

// Round 4
// 108.172 us; speedup vs baseline: 1.4042x; 1.4042x over previous
//
#include <hip/hip_runtime.h>
#include <stdint.h>

#define BATCH 8
#define SEQ   2048
#define DIM   256
#define NKV   64                 // kv tiles of 32 rows
#define KT    16384              // fragment bytes per 32-row tile (16 frags x 1KB)
#define NWT   16                 // 512/32 W k-tiles
#define VOFF  ((size_t)BATCH * NKV * KT)          // 8 MiB
#define WOFF  (VOFF + (size_t)BATCH * NKV * KT)   // 16 MiB

typedef __attribute__((ext_vector_type(8))) short bf16x8;
typedef __attribute__((ext_vector_type(4))) float f32x4;
typedef __attribute__((ext_vector_type(4))) unsigned int u32x4;

__device__ __forceinline__ unsigned short f2bf(float x) {
    unsigned u = __float_as_uint(x);
    unsigned r = u + 0x7fffu + ((u >> 16) & 1u);     // RNE
    return (unsigned short)(r >> 16);
}
__device__ __forceinline__ unsigned pack2(float a, float b) {
    return (unsigned)f2bf(a) | ((unsigned)f2bf(b) << 16);
}

// Build fragment-major bf16 images: each MFMA operand tile = 1KB block, lane-ordered,
// so the main loop's operand fetch is one coalesced 16B/lane global load (L2-resident).
// K frag (b,t,f=t2*8+kk): lane(g,nn) -> K[t*32 + (f>>3)*16 + nn][(f&7)*32 + g*8 .. +7]
// V frag (b,t,d):         lane(g,nn) -> V[t*32 + g*8 + j][d*16 + nn], j=0..7
// W frag (wt,d):          lane(g,nn) -> W[wt*32 + g*8 + j][d*16 + nn]
__global__ void prep_frags(const float* __restrict__ K, const float* __restrict__ V,
                           const float* __restrict__ W, uint8_t* __restrict__ ws) {
    const int bid = blockIdx.x, tid = threadIdx.x;
    const int lane = tid & 63, fb = tid >> 6, g = lane >> 4, nn = lane & 15;
    if (bid < BATCH * NKV) {
        const float* src = K + (size_t)bid * 32 * DIM;
        uint8_t* dst = ws + (size_t)bid * KT;
#pragma unroll
        for (int p = 0; p < 4; ++p) {
            int f = p * 4 + fb;
            int row = (f >> 3) * 16 + nn, col = (f & 7) * 32 + g * 8;
            float4 a = *(const float4*)(src + (size_t)row * DIM + col);
            float4 c = *(const float4*)(src + (size_t)row * DIM + col + 4);
            u32x4 u = {pack2(a.x, a.y), pack2(a.z, a.w), pack2(c.x, c.y), pack2(c.z, c.w)};
            *(u32x4*)(dst + f * 1024 + lane * 16) = u;
        }
    } else {
        const float* srcb;
        uint8_t* dst;
        if (bid < 2 * BATCH * NKV) {
            int id = bid - BATCH * NKV;
            srcb = V + (size_t)id * 32 * DIM;
            dst = ws + VOFF + (size_t)id * KT;
        } else {
            int wt = bid - 2 * BATCH * NKV;
            srcb = W + (size_t)wt * 32 * DIM;
            dst = ws + WOFF + (size_t)wt * KT;
        }
#pragma unroll
        for (int p = 0; p < 4; ++p) {
            int d = p * 4 + fb;
            float v[8];
#pragma unroll
            for (int j = 0; j < 8; ++j)
                v[j] = srcb[(size_t)(g * 8 + j) * DIM + d * 16 + nn];
            u32x4 u = {pack2(v[0], v[1]), pack2(v[2], v[3]),
                       pack2(v[4], v[5]), pack2(v[6], v[7])};
            *(u32x4*)(dst + d * 1024 + lane * 16) = u;
        }
    }
}

// smem: pbuf 4x1280 [0,5120) | cbuf f32[16][256] [5120,21504) |
//       cbn bf16[16][264] [21504,29952) | mws[4][16] | lws[4][16] | lgb[16]
#define SMEM_BYTES 30528

__launch_bounds__(256, 2)
__global__ void attn_main(const float* __restrict__ Q, const float* __restrict__ bias,
                          const uint8_t* __restrict__ ws, float* __restrict__ out) {
    __shared__ __align__(16) uint8_t smem[SMEM_BYTES];
    float* cbuf = (float*)(smem + 5120);
    uint8_t* cbn = smem + 21504;
    float* mws = (float*)(smem + 29952);
    float* lws = (float*)(smem + 30208);
    float* lgb = (float*)(smem + 30464);

    const int tid = threadIdx.x;
    const int wid = tid >> 6, lane = tid & 63, g = lane >> 4, nn = lane & 15;
    uint8_t* pbuf = smem + wid * 1280;
    const int b = blockIdx.x & 7, qg = blockIdx.x >> 3;   // batch -> XCD affinity
    const int q0 = qg * 16;

    // zero the merge accumulator (visibility ordered by the first __syncthreads below)
    {
        f32x4 z = {0.f, 0.f, 0.f, 0.f};
        float* p = cbuf + tid * 16;
#pragma unroll
        for (int i = 0; i < 4; ++i) *(f32x4*)(p + i * 4) = z;
    }

    // Q fragments (A-layout: row = nn, k = t8*32 + g*8 + j); identical in all 4 waves
    bf16x8 qf[8];
    {
        const float* qrow = Q + ((size_t)b * SEQ + q0 + nn) * DIM + g * 8;
#pragma unroll
        for (int t8 = 0; t8 < 8; ++t8) {
            float4 a = *(const float4*)(qrow + t8 * 32);
            float4 c = *(const float4*)(qrow + t8 * 32 + 4);
            union { bf16x8 v; unsigned u[4]; } tmp;
            tmp.u[0] = pack2(a.x, a.y); tmp.u[1] = pack2(a.z, a.w);
            tmp.u[2] = pack2(c.x, c.y); tmp.u[3] = pack2(c.z, c.w);
            qf[t8] = tmp.v;
        }
    }

    f32x4 ctx[16];
#pragma unroll
    for (int d = 0; d < 16; ++d) ctx[d] = (f32x4){0.f, 0.f, 0.f, 0.f};
    float m[4] = {-1e30f, -1e30f, -1e30f, -1e30f};
    float l[4] = {0.f, 0.f, 0.f, 0.f};
    const float c1 = 0.0625f * 1.44269504088896f;   // scale * log2(e)

    // each wave owns a contiguous KV quarter; no barriers in this loop
    const uint8_t* kws = ws + ((size_t)b * NKV + wid * 16) * KT + lane * 16;
    const uint8_t* vws = ws + VOFF + ((size_t)b * NKV + wid * 16) * KT + lane * 16;

    for (int t = 0; t < 16; ++t) {
        const uint8_t* kf = kws + (size_t)t * KT;
        const uint8_t* vf = vws + (size_t)t * KT;
        // ---- S = Q K^T ----
        f32x4 s[2];
#pragma unroll
        for (int t2 = 0; t2 < 2; ++t2) {
            bf16x8 kb[8];
#pragma unroll
            for (int kk = 0; kk < 8; ++kk)
                kb[kk] = *(const bf16x8*)(kf + (t2 * 8 + kk) * 1024);
            f32x4 acc = (f32x4){0.f, 0.f, 0.f, 0.f};
#pragma unroll
            for (int kk = 0; kk < 8; ++kk)
                acc = __builtin_amdgcn_mfma_f32_16x16x32_bf16(qf[kk], kb[kk], acc, 0, 0, 0);
            s[t2] = acc;
        }
        // ---- online softmax (row = g*4+r, kv dim = lanes nn of each half) ----
        float sc[4];
#pragma unroll
        for (int r = 0; r < 4; ++r) {
            float v = fmaxf(s[0][r], s[1][r]);
            v = fmaxf(v, __shfl_xor(v, 1));
            v = fmaxf(v, __shfl_xor(v, 2));
            v = fmaxf(v, __shfl_xor(v, 4));
            v = fmaxf(v, __shfl_xor(v, 8));
            float mn = fmaxf(m[r], v);
            sc[r] = exp2f((m[r] - mn) * c1);
            m[r] = mn;
        }
#pragma unroll
        for (int r = 0; r < 4; ++r) {
            float p0 = exp2f((s[0][r] - m[r]) * c1);
            float p1 = exp2f((s[1][r] - m[r]) * c1);
            float rs = p0 + p1;
            rs += __shfl_xor(rs, 1);
            rs += __shfl_xor(rs, 2);
            rs += __shfl_xor(rs, 4);
            rs += __shfl_xor(rs, 8);
            l[r] = l[r] * sc[r] + rs;
            *(unsigned short*)(pbuf + (g * 4 + r) * 80 + nn * 2)      = f2bf(p0);
            *(unsigned short*)(pbuf + (g * 4 + r) * 80 + 32 + nn * 2) = f2bf(p1);
        }
#pragma unroll
        for (int d = 0; d < 16; ++d) {
#pragma unroll
            for (int r = 0; r < 4; ++r) ctx[d][r] *= sc[r];
        }
        // ---- ctx += P V (P transposed via per-wave LDS; wave-internal, no barrier) ----
        bf16x8 pa = *(const bf16x8*)(pbuf + nn * 80 + g * 16);
#pragma unroll
        for (int d = 0; d < 16; ++d) {
            bf16x8 vv = *(const bf16x8*)(vf + d * 1024);
            ctx[d] = __builtin_amdgcn_mfma_f32_16x16x32_bf16(pa, vv, ctx[d], 0, 0, 0);
        }
    }

    // ---- merge the 4 KV-split partials (m, l, ctx) ----
    if (nn == 0) {
#pragma unroll
        for (int r = 0; r < 4; ++r) {
            mws[wid * 16 + g * 4 + r] = m[r];
            lws[wid * 16 + g * 4 + r] = l[r];
        }
    }
    __syncthreads();
    float sc[4];
#pragma unroll
    for (int r = 0; r < 4; ++r) {
        int row = g * 4 + r;
        float m0 = mws[row], m1 = mws[16 + row], m2 = mws[32 + row], m3 = mws[48 + row];
        float mg = fmaxf(fmaxf(m0, m1), fmaxf(m2, m3));
        float lg = lws[row]      * exp2f((m0 - mg) * c1)
                 + lws[16 + row] * exp2f((m1 - mg) * c1)
                 + lws[32 + row] * exp2f((m2 - mg) * c1)
                 + lws[48 + row] * exp2f((m3 - mg) * c1);
        sc[r] = exp2f((m[r] - mg) * c1);
        if (wid == 0 && nn == 0) lgb[row] = lg;
    }
    // sequential accumulate into cbuf (deterministic)
    for (int w = 0; w < 4; ++w) {
        if (wid == w) {
#pragma unroll
            for (int d = 0; d < 16; ++d) {
#pragma unroll
                for (int r = 0; r < 4; ++r) {
                    float* p = cbuf + (g * 4 + r) * 256 + d * 16 + nn;
                    *p += ctx[d][r] * sc[r];
                }
            }
        }
        __syncthreads();
    }
    // normalize + convert to bf16 image cbn[16][264]
    {
        int row = tid >> 4, c0 = (tid & 15) * 16;
        float il = 1.0f / lgb[row];
        const float* src = cbuf + row * 256 + c0;
        uint8_t* dp = cbn + row * 528 + c0 * 2;
#pragma unroll
        for (int i = 0; i < 2; ++i) {
            f32x4 a = *(const f32x4*)(src + i * 8);
            f32x4 c = *(const f32x4*)(src + i * 8 + 4);
            u32x4 u = {pack2(a[0] * il, a[1] * il), pack2(a[2] * il, a[3] * il),
                       pack2(c[0] * il, c[1] * il), pack2(c[2] * il, c[3] * il)};
            *(u32x4*)(dp + i * 16) = u;
        }
    }
    __syncthreads();

    // ---- epilogue: out = [ctxn, Q] @ W + b; wave wid owns output cols [wid*64, wid*64+64) ----
    f32x4 oacc[4];
#pragma unroll
    for (int dd = 0; dd < 4; ++dd) oacc[dd] = (f32x4){0.f, 0.f, 0.f, 0.f};
    const uint8_t* wws = ws + WOFF + lane * 16;
    for (int wt = 0; wt < NWT; ++wt) {
        bf16x8 af;
        if (wt < 8) af = *(const bf16x8*)(cbn + nn * 528 + wt * 64 + g * 16);
        else        af = qf[wt - 8];
#pragma unroll
        for (int dd = 0; dd < 4; ++dd) {
            bf16x8 wf = *(const bf16x8*)(wws + (size_t)(wt * 16 + wid * 4 + dd) * 1024);
            oacc[dd] = __builtin_amdgcn_mfma_f32_16x16x32_bf16(af, wf, oacc[dd], 0, 0, 0);
        }
    }
    float* obase = out + ((size_t)b * SEQ + q0) * DIM + wid * 64;
#pragma unroll
    for (int dd = 0; dd < 4; ++dd) {
        float bv = bias[wid * 64 + dd * 16 + nn];
#pragma unroll
        for (int r = 0; r < 4; ++r)
            obase[(size_t)(g * 4 + r) * DIM + dd * 16 + nn] = oacc[dd][r] + bv;
    }
}

extern "C" void kernel_launch(void* const* d_in, const int* in_sizes, int n_in,
                              void* d_out, int out_size, void* d_ws, size_t ws_size,
                              hipStream_t stream) {
    const float* Q    = (const float*)d_in[0];
    const float* K    = (const float*)d_in[1];
    const float* V    = (const float*)d_in[2];
    const float* W    = (const float*)d_in[3];
    const float* bias = (const float*)d_in[4];
    float* out = (float*)d_out;
    uint8_t* ws = (uint8_t*)d_ws;
    prep_frags<<<2 * BATCH * NKV + NWT, 256, 0, stream>>>(K, V, W, ws);
    attn_main<<<BATCH * SEQ / 16, 256, 0, stream>>>(Q, bias, ws, out);
}